// Round 18
// baseline (454.311 us; speedup 1.0000x reference)
//
#include <hip/hip_runtime.h>
#include <hip/hip_bf16.h>
#include <math.h>

#define BB 4
#define NN 1437
#define SS 56
#define PP 28
#define FIN 10
#define FFUT 6
#define HH 64
#define NBLK 2
#define TOPK 5
#define DD (SS*HH)     /* 3584 */
#define FD (PP*HH)     /* 1792 */
#define TOT (DD+FD)    /* 5376 */
#define MP 1536        /* padded M (12*128) */
#define KP 1472        /* padded K (46*32)  */
#define KC8 (KP/8)     /* 184 */
#define NT (KP/32)     /* 46 K-steps */
#define WIMG_SZ 16384  /* shorts per mixer-block weight image */

typedef __attribute__((ext_vector_type(8))) __bf16 bf16x8;
typedef __attribute__((ext_vector_type(4))) float  f32x4;
typedef unsigned long long u64;

// h: permuted intra-row layout, element (s,f) at s*64 + (f&15)*4 + (f>>4).
// spat0 (bmm iter0 out): same permuted layout, bf16, row stride TOT, in feats16's h-region.
// comb8: UNNORMALIZED fp8 e4m3, K-PACKED [b][kc(184)][MP][8]; per-row inv in bmm epilogue.
// xpg8: fp8 e4m3 K-packed [b][KC8][DD][8] bytes.

__device__ __forceinline__ float gelu_fast(float x){
    float x2 = x*x;
    float u  = __builtin_fmaf(0.044715f*x2, x, x);
    float e  = __builtin_amdgcn_exp2f(2.3022077f*u);
    float r  = __builtin_amdgcn_rcpf(e+1.f);
    return x - x*r;
}
template<int C>
__device__ __forceinline__ float dppadd(float v){
    int x = __builtin_amdgcn_mov_dpp(__float_as_int(v), C, 0xF, 0xF, true);
    return v + __int_as_float(x);
}
__device__ __forceinline__ float row16_sum(float v){
    v = dppadd<0xB1>(v);
    v = dppadd<0x4E>(v);
    v = dppadd<0x141>(v);
    v = dppadd<0x140>(v);
    return v;
}
__device__ __forceinline__ float wave_sum64(float v){
    v = row16_sum(v);
    v += __shfl_xor(v,16,64);
    v += __shfl_xor(v,32,64);
    return v;
}
__device__ __forceinline__ void async_load16(const void* g, void* l){
    __builtin_amdgcn_global_load_lds(
        (const __attribute__((address_space(1))) void*)g,
        (__attribute__((address_space(3))) void*)l, 16, 0, 0);
}
__device__ __forceinline__ unsigned short f2bf(float x){
    unsigned int u = __float_as_uint(x);
    unsigned int r = (u + 0x7fffu + ((u>>16)&1u)) >> 16;
    return (unsigned short)r;
}
__device__ __forceinline__ unsigned int cvtpk_bf16(float lo, float hi){
    unsigned int r;
    asm("v_cvt_pk_bf16_f32 %0, %1, %2" : "=v"(r) : "v"(lo), "v"(hi));
    return r;
}
__device__ __forceinline__ float bf2f(unsigned short u){
    return __uint_as_float(((unsigned int)u)<<16);
}
__device__ __forceinline__ unsigned char f2fp8(float x){
    return (unsigned char)(__builtin_amdgcn_cvt_pk_fp8_f32(x, 0.f, 0, false) & 0xFF);
}
__device__ __forceinline__ unsigned int pack4fp8(float a, float b, float c, float d){
    int lo = __builtin_amdgcn_cvt_pk_fp8_f32(a, b, 0, false);
    return (unsigned int)__builtin_amdgcn_cvt_pk_fp8_f32(c, d, lo, true);
}
__device__ __forceinline__ u64 umax64(u64 a, u64 b){return a>b?a:b;}
__device__ __forceinline__ u64 umin64(u64 a, u64 b){return a<b?a:b;}

#define INS5(a0,a1,a2,a3,a4,x) do{ u64 t_=(x); \
    u64 n0_=umax64(a0,t_), t1_=umin64(a0,t_); \
    u64 n1_=umax64(a1,t1_), t2_=umin64(a1,t1_); \
    u64 n2_=umax64(a2,t2_), t3_=umin64(a2,t2_); \
    u64 n3_=umax64(a3,t3_), t4_=umin64(a3,t3_); \
    u64 n4_=umax64(a4,t4_); \
    a0=n0_;a1=n1_;a2=n2_;a3=n3_;a4=n4_; }while(0)

#define MERGE5(a0,a1,a2,a3,a4,b0,b1,b2,b3,b4) do{ \
    u64 o0_=umax64(a0,(b0)); \
    u64 o1_=umax64(umax64((b1),umin64(a0,(b0))),a1); \
    u64 o2_=umax64(umax64((b2),umin64(a0,(b1))),umax64(umin64(a1,(b0)),a2)); \
    u64 o3_=umax64(umax64((b3),umin64(a0,(b2))),umax64(umin64(a1,(b1)),umax64(umin64(a2,(b0)),a3))); \
    u64 o4_=umax64(umax64((b4),umin64(a0,(b3))),umax64(umax64(umin64(a1,(b2)),umin64(a2,(b1))),umax64(umin64(a3,(b0)),a4))); \
    a0=o0_;a1=o1_;a2=o2_;a3=o3_;a4=o4_; }while(0)

// ------- front -------
__global__ __launch_bounds__(256) void k_front(
    const float* __restrict__ x, const float* __restrict__ fpw, const float* __restrict__ fpb,
    const float* __restrict__ lng, const float* __restrict__ lnb,
    const float* __restrict__ nemb,
    const float* __restrict__ qw, const float* __restrict__ qb,
    const float* __restrict__ kw, const float* __restrict__ kb,
    float* __restrict__ h,
    unsigned short* __restrict__ qpack, unsigned short* __restrict__ kpack)
{
    int bn = blockIdx.x; int n = bn % NN;
    int tid=threadIdx.x; int lane=tid&63; int wv=tid>>6;
    __shared__ float xin[SS*FIN];
    __shared__ float wlds[HH*FIN];
    __shared__ float rw[SS];
    __shared__ float rsum;
    __shared__ float red[4][HH];
    __shared__ float ctxs[HH];
    for (int i=tid;i<SS*FIN;i+=256) xin[i]=x[(size_t)bn*SS*FIN+i];
    for (int i=tid;i<HH*FIN;i+=256) wlds[i]=fpw[i];
    if (tid<SS) rw[tid]=expf(-(float)(SS-tid)/14.0f);
    __syncthreads();
    if (tid==0){ float s=0.f; for(int i=0;i<SS;++i) s+=rw[i]; rsum=s; }
    __syncthreads();
    float inv_rs = 1.0f/rsum;
    float ev = nemb[(size_t)n*HH+lane];
    float ss = wave_sum64(ev*ev);
    float el = ev / fmaxf(sqrtf(ss), 1e-12f);
    float gg=lng[lane], bv=lnb[lane], fb0=fpb[lane];
    int paddr = (lane&15)*4 + (lane>>4);
    float cacc=0.f;
    for (int s=wv;s<SS;s+=4){
        float v=fb0;
        #pragma unroll
        for (int c=0;c<FIN;++c) v += xin[s*FIN+c]*wlds[lane*FIN+c];
        float m = wave_sum64(v)*(1.f/HH);
        float d = v-m;
        float va = wave_sum64(d*d)*(1.f/HH);
        float hn = d*rsqrtf(va+1e-5f)*gg + bv + el;
        h[((size_t)bn*SS+s)*HH + paddr]=hn;
        cacc += hn * rw[s]*inv_rs;
    }
    red[wv][lane]=cacc;
    __syncthreads();
    if (wv==0) ctxs[lane]=red[0][lane]+red[1][lane]+red[2][lane]+red[3][lane];
    __syncthreads();
    if (wv<2){
        const float* wmat = (wv==0)? qw : kw;
        const float* bvec = (wv==0)? qb : kb;
        unsigned short* dstp = (wv==0)? qpack : kpack;
        const float4* wr_ = reinterpret_cast<const float4*>(wmat + (size_t)lane*HH);
        float acc = bvec[lane];
        #pragma unroll 4
        for (int t=0;t<16;++t){
            float4 wv4=wr_[t];
            acc += wv4.x*ctxs[4*t] + wv4.y*ctxs[4*t+1] + wv4.z*ctxs[4*t+2] + wv4.w*ctxs[4*t+3];
        }
        int b = bn/NN, m = bn%NN;
        size_t off = (size_t)b*8*MP*8 + (size_t)(lane>>3)*MP*8 + (size_t)m*8 + (lane&7);
        dstp[off]=f2bf(acc);
    }
}

// ---- adjsum ----
__global__ __launch_bounds__(256) void k_adjsum(
    const float* __restrict__ adj, float* __restrict__ adjsum)
{
    int m = blockIdx.x*4 + (threadIdx.x>>6);
    int lane = threadIdx.x & 63;
    if (m >= NN) return;
    const float* row = adj + (size_t)m*NN;
    float s=0.f;
    for (int n=lane;n<NN;n+=64) s += row[n];
    s = wave_sum64(s);
    if (lane==0) adjsum[m]=s;
}

// ---- fused QK^T + top-5 ----
__global__ __launch_bounds__(256) void k_qkt_top5(
    const unsigned short* __restrict__ qp, const unsigned short* __restrict__ kp,
    const float* __restrict__ adjsum, const float* __restrict__ galpha,
    int* __restrict__ meta_idx, float* __restrict__ meta_p, float* __restrict__ meta_inv)
{
    int m0 = blockIdx.x*32; int b = blockIdx.y;
    int tid=threadIdx.x, lane=tid&63, w=tid>>6;
    int g=lane>>4, c15=lane&15;
    int wr=w>>1, wc=w&1;
    __shared__ u64 mls[64][5];

    const unsigned short* qb2 = qp + (size_t)b*8*MP*8;
    const unsigned short* kb2 = kp + (size_t)b*8*MP*8;
    bf16x8 af0 = *(const bf16x8*)(qb2 + ((size_t)(0*4+g)*MP + m0+wr*16+c15)*8);
    bf16x8 af1 = *(const bf16x8*)(qb2 + ((size_t)(1*4+g)*MP + m0+wr*16+c15)*8);

    u64 A0=0,A1=0,A2=0,A3=0,A4=0;
    u64 B0=0,B1=0,B2=0,B3=0,B4=0;
    u64 C0=0,C1=0,C2=0,C3=0,C4=0;
    u64 D0=0,D1=0,D2=0,D3=0,D4=0;

    for (int t=0;t<12;++t){
        int n0 = t*128;
        f32x4 acc[4];
        #pragma unroll
        for (int j=0;j<4;++j) acc[j]=(f32x4){0.f,0.f,0.f,0.f};
        #pragma unroll
        for (int j=0;j<4;++j){
            bf16x8 b0 = *(const bf16x8*)(kb2 + ((size_t)(0*4+g)*MP + n0+wc*64+j*16+c15)*8);
            bf16x8 b1 = *(const bf16x8*)(kb2 + ((size_t)(1*4+g)*MP + n0+wc*64+j*16+c15)*8);
            acc[j]=__builtin_amdgcn_mfma_f32_16x16x32_bf16(af0,b0,acc[j],0,0,0);
            acc[j]=__builtin_amdgcn_mfma_f32_16x16x32_bf16(af1,b1,acc[j],0,0,0);
        }
        #pragma unroll
        for (int j=0;j<4;++j){
            int n = n0 + wc*64 + j*16 + c15;
            bool ok = (n < NN);
            unsigned int lowk = 0xFFFFFFFFu - (unsigned)n;
            #define MKKEY(Q) ({ \
                float v_ = acc[j][Q]*0.125f; \
                v_ = fminf(fmaxf(v_,0.f),10.f); \
                ok ? (((u64)__float_as_uint(v_)<<32)|(u64)lowk) : 0ULL; })
            { u64 k_=MKKEY(0); INS5(A0,A1,A2,A3,A4,k_); }
            { u64 k_=MKKEY(1); INS5(B0,B1,B2,B3,B4,k_); }
            { u64 k_=MKKEY(2); INS5(C0,C1,C2,C3,C4,k_); }
            { u64 k_=MKKEY(3); INS5(D0,D1,D2,D3,D4,k_); }
            #undef MKKEY
        }
    }
    #pragma unroll
    for (int off=1; off<16; off<<=1){
        u64 t0,t1,t2,t3,t4;
        t0=__shfl_xor(A0,off,64); t1=__shfl_xor(A1,off,64); t2=__shfl_xor(A2,off,64); t3=__shfl_xor(A3,off,64); t4=__shfl_xor(A4,off,64);
        MERGE5(A0,A1,A2,A3,A4,t0,t1,t2,t3,t4);
        t0=__shfl_xor(B0,off,64); t1=__shfl_xor(B1,off,64); t2=__shfl_xor(B2,off,64); t3=__shfl_xor(B3,off,64); t4=__shfl_xor(B4,off,64);
        MERGE5(B0,B1,B2,B3,B4,t0,t1,t2,t3,t4);
        t0=__shfl_xor(C0,off,64); t1=__shfl_xor(C1,off,64); t2=__shfl_xor(C2,off,64); t3=__shfl_xor(C3,off,64); t4=__shfl_xor(C4,off,64);
        MERGE5(C0,C1,C2,C3,C4,t0,t1,t2,t3,t4);
        t0=__shfl_xor(D0,off,64); t1=__shfl_xor(D1,off,64); t2=__shfl_xor(D2,off,64); t3=__shfl_xor(D3,off,64); t4=__shfl_xor(D4,off,64);
        MERGE5(D0,D1,D2,D3,D4,t0,t1,t2,t3,t4);
    }
    if (c15==0){
        int rb = wr*16 + g*4;
        mls[(rb+0)*2+wc][0]=A0; mls[(rb+0)*2+wc][1]=A1; mls[(rb+0)*2+wc][2]=A2; mls[(rb+0)*2+wc][3]=A3; mls[(rb+0)*2+wc][4]=A4;
        mls[(rb+1)*2+wc][0]=B0; mls[(rb+1)*2+wc][1]=B1; mls[(rb+1)*2+wc][2]=B2; mls[(rb+1)*2+wc][3]=B3; mls[(rb+1)*2+wc][4]=B4;
        mls[(rb+2)*2+wc][0]=C0; mls[(rb+2)*2+wc][1]=C1; mls[(rb+2)*2+wc][2]=C2; mls[(rb+2)*2+wc][3]=C3; mls[(rb+2)*2+wc][4]=C4;
        mls[(rb+3)*2+wc][0]=D0; mls[(rb+3)*2+wc][1]=D1; mls[(rb+3)*2+wc][2]=D2; mls[(rb+3)*2+wc][3]=D3; mls[(rb+3)*2+wc][4]=D4;
    }
    __syncthreads();
    if (tid < 32){
        int m = m0 + tid;
        if (m < NN){
            u64 u0=mls[tid*2][0],u1=mls[tid*2][1],u2=mls[tid*2][2],u3=mls[tid*2][3],u4=mls[tid*2][4];
            MERGE5(u0,u1,u2,u3,u4, mls[tid*2+1][0],mls[tid*2+1][1],mls[tid*2+1][2],mls[tid*2+1][3],mls[tid*2+1][4]);
            float s0=__uint_as_float((unsigned)(u0>>32)), s1=__uint_as_float((unsigned)(u1>>32)),
                  s2=__uint_as_float((unsigned)(u2>>32)), s3=__uint_as_float((unsigned)(u3>>32)),
                  s4=__uint_as_float((unsigned)(u4>>32));
            int i0=(int)(0xFFFFFFFFu-(unsigned)u0), i1=(int)(0xFFFFFFFFu-(unsigned)u1),
                i2=(int)(0xFFFFFFFFu-(unsigned)u2), i3=(int)(0xFFFFFFFFu-(unsigned)u3),
                i4=(int)(0xFFFFFFFFu-(unsigned)u4);
            float e0=1.f, e1=expf(s1-s0), e2=expf(s2-s0), e3=expf(s3-s0), e4=expf(s4-s0);
            float den=e0+e1+e2+e3+e4;
            float alpha=1.f/(1.f+expf(-galpha[0]));
            float oma=(1.f-alpha)/den;
            size_t base = ((size_t)b*NN + m)*5;
            meta_idx[base+0]=i0; meta_idx[base+1]=i1; meta_idx[base+2]=i2; meta_idx[base+3]=i3; meta_idx[base+4]=i4;
            meta_p[base+0]=oma*e0; meta_p[base+1]=oma*e1; meta_p[base+2]=oma*e2; meta_p[base+3]=oma*e3; meta_p[base+4]=oma*e4;
            meta_inv[(size_t)b*NN+m] = 1.f/fmaxf(alpha*adjsum[m] + (1.f-alpha), 1e-12f);
        }
    }
}

// ---- blend: comb8 K-packed [b][kc][MP][8] = fp8(alpha*adj + top5 fixups), UNNORMALIZED ----
__global__ __launch_bounds__(256) void k_blend(
    const float* __restrict__ adj, const float* __restrict__ galpha,
    const int* __restrict__ meta_idx, const float* __restrict__ meta_p,
    unsigned char* __restrict__ comb8)
{
    int bid = blockIdx.x;
    int xx = bid & 7, ii = bid >> 3;
    int lin = (xx < 4) ? xx*719 + ii : 2876 + (xx-4)*718 + ii;   // 5748 = 4*719+4*718
    int b = lin / NN, m = lin - b*NN;
    int tid=threadIdx.x;
    size_t base = ((size_t)b*NN + m)*5;
    int i0=meta_idx[base+0], i1=meta_idx[base+1], i2=meta_idx[base+2],
        i3=meta_idx[base+3], i4=meta_idx[base+4];
    float p0=meta_p[base+0], p1=meta_p[base+1], p2=meta_p[base+2],
          p3=meta_p[base+3], p4=meta_p[base+4];
    float alpha=1.f/(1.f+expf(-galpha[0]));
    const float* arow = adj + (size_t)m*NN;
    unsigned char* dst = comb8 + (size_t)b*KC8*(size_t)MP*8;
    for (int n4=tid; n4<KP/4; n4+=256){
        float v[4];
        #pragma unroll
        for (int k=0;k<4;++k){
            int n = n4*4+k;
            float vv = 0.f;
            if (n<NN){
                vv = alpha*arow[n];
                vv += (n==i0)?p0:0.f;
                vv += (n==i1)?p1:0.f;
                vv += (n==i2)?p2:0.f;
                vv += (n==i3)?p3:0.f;
                vv += (n==i4)?p4:0.f;
            }
            v[k]=vv;
        }
        int kc = n4>>1, half = n4&1;
        *reinterpret_cast<unsigned int*>(dst + ((size_t)kc*MP + m)*8 + half*4) =
            pack4fp8(v[0],v[1],v[2],v[3]);
    }
}

// ---- prep: weight images ----
__global__ __launch_bounds__(256) void k_prepw(
    const float* __restrict__ wk, const float* __restrict__ mk,
    const float* __restrict__ tw, const float* __restrict__ fw,
    const float* __restrict__ sw, unsigned short* __restrict__ wimg)
{
    int i = blockIdx.x; int tid = threadIdx.x;
    const float* wki = wk + i*7;
    const float* mki = mk + i*28;
    const float* twi = tw + i*SS*SS;
    const float* fwi = fw + i*HH*HH;
    const float* swi = sw + i*HH*HH;
    unsigned short* o = wimg + (size_t)i*WIMG_SZ;
    for (int e=tid; e<4096; e+=256){
        int r = e>>6, k = e&63;
        int swz = ((k*2) ^ ((r&7)<<4)) >> 1;
        float mv = 0.f;
        if (r<SS && k<SS){
            int a = k-r+3;  if (a>=0 && a<7)  mv += wki[a];
            int b2= k-r+13; if (b2>=0 && b2<28) mv += mki[b2];
        }
        o[r*64 + swz] = f2bf(mv);
        float tv = (r<SS && k<SS) ? twi[r*SS+k] : 0.f;
        o[4096 + r*64 + swz] = f2bf(tv);
        int pk = (k>>3)*512 + r*8 + (k&7);
        o[8192  + pk] = f2bf(fwi[r*HH+k]);
        o[12288 + pk] = f2bf(swi[r*HH+k]);
    }
}

// ---- prep head ----
__global__ __launch_bounds__(256) void k_prep_head(
    const float* __restrict__ hw, __hip_bfloat16* __restrict__ hw16)
{
    int i = blockIdx.x*256 + threadIdx.x;
    int r = i / TOT, k = i - r*TOT;
    float v = (r<PP) ? hw[(size_t)r*TOT + k] : 0.f;
    hw16[i] = __float2bfloat16(v);
}

// ---- fut ----
__global__ __launch_bounds__(256) void k_fut(
    const float* __restrict__ xf, const float* __restrict__ fw,
    const float* __restrict__ fbias, __hip_bfloat16* __restrict__ feats)
{
    int bn=blockIdx.x, tid=threadIdx.x;
    __shared__ float fwl[HH*FFUT];
    __shared__ float fbl[HH];
    __shared__ float xfl[PP*FFUT];
    for (int i=tid;i<HH*FFUT;i+=256) fwl[i]=fw[i];
    if (tid<HH) fbl[tid]=fbias[tid];
    for (int i=tid;i<PP*FFUT;i+=256) xfl[i]=xf[(size_t)bn*PP*FFUT+i];
    __syncthreads();
    __hip_bfloat16* dst = feats + (size_t)bn*TOT + DD;
    for (int q=tid;q<FD;q+=256){
        int pp=q>>6, hh2=q&63;
        float v=fbl[hh2];
        #pragma unroll
        for (int c2=0;c2<FFUT;++c2) v += xfl[pp*FFUT+c2]*fwl[hh2*FFUT+c2];
        dst[q]=__float2bfloat16(v);
    }
}

// ---------------- MFMA mixer: 2 nodes/block, 512 threads, 8 waves ----------------
__global__ __launch_bounds__(512) void k_mixer2(
    float* __restrict__ h, unsigned char* __restrict__ xpg8,
    const unsigned short* __restrict__ spat_in,
    const unsigned short* __restrict__ wimg,
    const float* __restrict__ lncg, const float* __restrict__ lncb,
    const float* __restrict__ lntg, const float* __restrict__ lntb,
    const float* __restrict__ lnfg, const float* __restrict__ lnfb,
    const float* __restrict__ lnsg, const float* __restrict__ lnsb,
    const float* __restrict__ tb, const float* __restrict__ fb)
{
    // 2874 pair-blocks = 2*360 + 6*359, XCD-chunked bijective map
    int bid = blockIdx.x;
    int xx = bid & 7, ii = bid >> 3;
    int lin = (xx < 2) ? xx*360 + ii : 720 + (xx-2)*359 + ii;
    int tid=threadIdx.x, lane=tid&63, w=tid>>6;        // w in 0..7
    int half = w>>2, wloc = w&3;
    int bn = 2*lin + half;
    int g=lane>>4, c=lane&15;
    __shared__ unsigned short wbuf[2][4096];
    __shared__ unsigned short xs[2][2][4096];          // [half][buf]
    __shared__ float prm[640];

    const char* wsrc=(const char*)wimg;
#define LOADW(SLOTB, BUFP) \
    async_load16(wsrc+(size_t)(SLOTB)+((size_t)tid)*16, (char*)(BUFP)+tid*16)

    LOADW(0,    wbuf[0]);
    LOADW(8192, wbuf[1]);
    if (tid<64){
        prm[tid]      =lncg[tid]; prm[64+tid] =lncb[tid];
        prm[128+tid]  =lntg[tid]; prm[192+tid]=lntb[tid];
        prm[256+tid]  =lnfg[tid]; prm[320+tid]=lnfb[tid];
        prm[384+tid]  =lnsg[tid]; prm[448+tid]=lnsb[tid];
        prm[512+tid]  =(tid<SS)?tb[tid]:0.f;
        prm[576+tid]  =fb[tid];
    }
    float xl[4][4];
    float* hb = h + (size_t)bn*DD;
    int srow = 16*wloc + 4*g;
    #pragma unroll
    for (int q=0;q<4;++q){
        int s=srow+q;
        if (s<SS){
            const float4 v4 = *reinterpret_cast<const float4*>(hb + s*HH + c*4);
            float a0=v4.x, a1=v4.y, a2=v4.z, a3=v4.w;
            if (spat_in){
                ushort4 sv = *reinterpret_cast<const ushort4*>(spat_in + (size_t)bn*TOT + s*HH + c*4);
                a0 += bf2f(sv.x); a1 += bf2f(sv.y); a2 += bf2f(sv.z); a3 += bf2f(sv.w);
            }
            xl[q][0]=a0; xl[q][1]=a1; xl[q][2]=a2; xl[q][3]=a3;
        } else {
            xl[q][0]=0.f; xl[q][1]=0.f; xl[q][2]=0.f; xl[q][3]=0.f;
        }
    }
    __syncthreads();   // S0: prm ready

    float xn[4][4];
    f32x4 acc[4];

#define LNSTAGE(GOFF,BOFF) do{ \
    _Pragma("unroll") \
    for (int q=0;q<4;++q){ \
        float sv = xl[q][0]+xl[q][1]+xl[q][2]+xl[q][3]; \
        float s2 = xl[q][0]*xl[q][0]+xl[q][1]*xl[q][1]+xl[q][2]*xl[q][2]+xl[q][3]*xl[q][3]; \
        sv = row16_sum(sv); \
        s2 = row16_sum(s2); \
        float mn = sv*(1.f/64.f); \
        float var = s2*(1.f/64.f)-mn*mn; \
        float rstd = rsqrtf(var+1e-5f); \
        bool ok = (srow+q)<SS; \
        _Pragma("unroll") \
        for (int tj=0;tj<4;++tj){ \
            float v=(xl[q][tj]-mn)*rstd*prm[(GOFF)+tj*16+c]+prm[(BOFF)+tj*16+c]; \
            xn[q][tj]= ok ? v : 0.f; \
        } \
    } }while(0)

#define WRITE_XNP(XS) do{ \
    _Pragma("unroll") \
    for (int qp=0;qp<2;++qp){ \
        int s0=srow+2*qp; \
        _Pragma("unroll") \
        for (int tj=0;tj<4;++tj){ \
            unsigned int pv = cvtpk_bf16(xn[2*qp][tj], xn[2*qp+1][tj]); \
            *(unsigned int*)((char*)(XS) + ((s0>>3)*1024 + (tj*16+c)*16 + (s0&7)*2)) = pv; \
        } \
    } }while(0)

#define WRITE_XNR(XS) do{ \
    _Pragma("unroll") \
    for (int q=0;q<4;++q){ int s=srow+q; \
        _Pragma("unroll") \
        for (int tj=0;tj<4;++tj){ \
            *(unsigned short*)((char*)(XS) + s*128 + (((tj*16+c)*2) ^ ((s&7)<<4))) = f2bf(xn[q][tj]); \
        } \
    } }while(0)

#define MM(APTR,BPTR) do{ \
    _Pragma("unroll") \
    for (int tj=0;tj<4;++tj) acc[tj]=(f32x4){0.f,0.f,0.f,0.f}; \
    _Pragma("unroll") \
    for (int kc=0;kc<2;++kc){ \
        int arow=16*wloc+c; \
        bf16x8 af=*(const bf16x8*)((const char*)(APTR)+arow*128+((kc*64+g*16)^((arow&7)<<4))); \
        _Pragma("unroll") \
        for (int tj=0;tj<4;++tj){ \
            bf16x8 bf2=*(const bf16x8*)((const char*)(BPTR)+(kc*4+g)*1024+(tj*16+c)*16); \
            acc[tj]=__builtin_amdgcn_mfma_f32_16x16x32_bf16(af,bf2,acc[tj],0,0,0); \
        } \
    } }while(0)

    // ---- conv (banded matmul) ----
    LNSTAGE(0,64); WRITE_XNP(xs[half][0]);
    __syncthreads();   // S1
    MM(&wbuf[0][0], xs[half][0]);
    #pragma unroll
    for (int q=0;q<4;++q)
        #pragma unroll
        for (int tj=0;tj<4;++tj) xl[q][tj]+=acc[tj][q];
    // ---- temporal ----
    LNSTAGE(128,192); WRITE_XNP(xs[half][1]);
    __syncthreads();   // S2 (wbuf0 free)
    LOADW(16384, wbuf[0]);   // feature weights (one 512-lane inst)
    MM(&wbuf[1][0], xs[half][1]);
    #pragma unroll
    for (int q=0;q<4;++q){
        float tbv=prm[512+srow+q];
        #pragma unroll
        for (int tj=0;tj<4;++tj) xl[q][tj]+=gelu_fast(acc[tj][q]+tbv);
    }
    // ---- feature ----
    LNSTAGE(256,320); WRITE_XNR(xs[half][0]);
    __syncthreads();   // S3 (feature-load drained; wbuf1 free)
    LOADW(24576, wbuf[1]);   // spatial weights
    MM(xs[half][0], &wbuf[0][0]);
    #pragma unroll
    for (int q=0;q<4;++q)
        #pragma unroll
        for (int tj=0;tj<4;++tj) xl[q][tj]+=gelu_fast(acc[tj][q]+prm[576+tj*16+c]);
    // ---- spatial projection ----
    LNSTAGE(384,448); WRITE_XNR(xs[half][1]);
    __syncthreads();   // S4 (spatial-load drained)
    MM(xs[half][1], &wbuf[1][0]);
    int b_=bn/NN, n_=bn%NN;
    unsigned char* xpo = xpg8 + ((size_t)b_*KC8 + (size_t)(n_>>3))*(size_t)DD*8 + (n_&7);
    #pragma unroll
    for (int q=0;q<4;++q){
        int s=srow+q;
        if (s<SS){
            float4 hv; hv.x=xl[q][0]; hv.y=xl[q][1]; hv.z=xl[q][2]; hv.w=xl[q][3];
            *reinterpret_cast<float4*>(hb + s*HH + c*4) = hv;
            #pragma unroll
            for (int tj=0;tj<4;++tj){
                int d = s*HH + tj*16 + c;
                xpo[(size_t)d*8] = f2fp8(acc[tj][q]);
            }
        }
    }
#undef LNSTAGE
#undef WRITE_XNP
#undef WRITE_XNR
#undef MM
#undef LOADW
}

// ---- spatial bmm via fp8 MFMA; all-16B coalesced staging ----
__global__ __launch_bounds__(256,8) void k_bmm_mfma(
    const unsigned char* __restrict__ comb8,   // K-packed [b][kc][MP][8]
    const unsigned char* __restrict__ xpg8,    // K-packed [b][kc][DD][8]
    const float* __restrict__ sb,
    const float* __restrict__ h,
    const float* __restrict__ meta_inv,
    unsigned short* __restrict__ spat_out,
    __hip_bfloat16* __restrict__ feats_out)
{
    __shared__ unsigned char As8[3][2048];
    __shared__ unsigned char Bs8[3][4096];
    __shared__ float sinv[64];

    int bid = blockIdx.x;
    int wg = (bid & 7)*336 + (bid >> 3);
    int bm = wg % 24; int tmp2 = wg / 24; int bd = tmp2 % 28; int b = tmp2 / 28;
    int tid=threadIdx.x, lane=tid&63, w=tid>>6;
    int g=lane>>4, c=lane&15;
    int wr=w>>1, wc=w&1;
    int m0=bm*64, d0=bd*128;

    const unsigned char* cbK = comb8 + (size_t)b*KC8*(size_t)MP*8;
    const unsigned char* xb  = xpg8  + (size_t)b*KC8*(size_t)DD*8;

    int l32 = lane & 31;
    const unsigned char* srcA = cbK + ((size_t)w*MP + m0 + l32*2)*8;
    const size_t ASTEP = (size_t)4*MP*8;
    int klB = tid>>6, dpair = tid&63;
    const unsigned char* srcB = xb + ((size_t)klB*DD + d0 + dpair*2)*8;
    const size_t BSTEP = (size_t)4*DD*8;

    if (tid < 64){
        int m = m0 + tid;
        sinv[tid] = (m < NN) ? meta_inv[(size_t)b*NN + m] : 0.f;
    }

    f32x4 acc[2][4];
    #pragma unroll
    for (int i=0;i<2;++i)
        #pragma unroll
        for (int j=0;j<4;++j) acc[i][j]=(f32x4){0.f,0.f,0.f,0.f};

    int aoff[2], boff[4];
    #pragma unroll
    for (int i=0;i<2;++i) aoff[i] = g*512 + (32*wr + 16*i + c)*8;
    #pragma unroll
    for (int j=0;j<4;++j) boff[j] = g*1024 + (64*wc + 16*j + c)*8;

#define STAGE(BUF,T) do { \
    if (lane < 32) async_load16(srcA + (size_t)(T)*ASTEP, (char*)As8[BUF] + w*512 + l32*16); \
    async_load16(srcB + (size_t)(T)*BSTEP, (char*)Bs8[BUF] + tid*16); } while(0)

    STAGE(0,0); STAGE(1,1);
    asm volatile("s_waitcnt vmcnt(2) lgkmcnt(0)" ::: "memory");
    __builtin_amdgcn_s_barrier();

    int cur=0;
    for (int t=0;t<NT;++t){
        if (t+2<NT){
            int nb = cur+2; if (nb>=3) nb-=3;
            STAGE(nb, t+2);
        }
        const char* Ab=(const char*)As8[cur];
        const char* Bb=(const char*)Bs8[cur];
        u64 af[2], bfv[4];
        #pragma unroll
        for (int i=0;i<2;++i) af[i]=*(const u64*)(Ab + aoff[i]);
        #pragma unroll
        for (int j=0;j<4;++j) bfv[j]=*(const u64*)(Bb + boff[j]);
        #pragma unroll
        for (int i=0;i<2;++i)
            #pragma unroll
            for (int j=0;j<4;++j)
                acc[i][j]=__builtin_amdgcn_mfma_f32_16x16x32_fp8_fp8((long)af[i],(long)bfv[j],acc[i][j],0,0,0);
        if (t+2<NT) asm volatile("s_waitcnt vmcnt(2)" ::: "memory");
        else        asm volatile("s_waitcnt vmcnt(0)" ::: "memory");
        __builtin_amdgcn_s_barrier();
        ++cur; if (cur>=3) cur=0;
    }
#undef STAGE

    int row_b = m0 + 32*wr + g*4;
    int s2 = 2*bd + wc;
    float sb0=sb[c], sb1=sb[16+c], sb2=sb[32+c], sb3=sb[48+c];
    #pragma unroll
    for (int i=0;i<2;++i){
        #pragma unroll
        for (int q=0;q<4;++q){
            int m = row_b + 16*i + q;
            if (m < NN){
                float inv = sinv[32*wr + g*4 + 16*i + q];
                if (spat_out){
                    ushort4 pv;
                    pv.x = f2bf(inv*acc[i][0][q] + sb0);
                    pv.y = f2bf(inv*acc[i][1][q] + sb1);
                    pv.z = f2bf(inv*acc[i][2][q] + sb2);
                    pv.w = f2bf(inv*acc[i][3][q] + sb3);
                    *reinterpret_cast<ushort4*>(spat_out + ((size_t)b*NN+m)*TOT + s2*HH + c*4) = pv;
                } else {
                    const float* hp = h + ((size_t)b*NN+m)*DD + s2*HH + c*4;
                    float4 hv = *reinterpret_cast<const float4*>(hp);
                    float nv0 = hv.x + inv*acc[i][0][q] + sb0;
                    float nv1 = hv.y + inv*acc[i][1][q] + sb1;
                    float nv2 = hv.z + inv*acc[i][2][q] + sb2;
                    float nv3 = hv.w + inv*acc[i][3][q] + sb3;
                    size_t fr = ((size_t)b*NN+m)*TOT + (size_t)bd*128 + wc*64;
                    feats_out[fr + c]      = __float2bfloat16(nv0);
                    feats_out[fr + 16 + c] = __float2bfloat16(nv1);
                    feats_out[fr + 32 + c] = __float2bfloat16(nv2);
                    feats_out[fr + 48 + c] = __float2bfloat16(nv3);
                }
            }
        }
    }
}

// ---------------- head GEMM (4 independent acc chains) ----------------
__global__ __launch_bounds__(256) void k_head_mfma(
    const __hip_bfloat16* __restrict__ feats, const __hip_bfloat16* __restrict__ hw16,
    const float* __restrict__ hb, float* __restrict__ out)
{
    int tid=threadIdx.x, lane=tid&63, w=tid>>6;
    int g=lane>>4, c=lane&15;
    int m0=blockIdx.x*32;
    int rt=w>>1, pt=w&1;
    int arow = m0 + rt*16 + c;
    if (arow > BB*NN-1) arow = BB*NN-1;
    const char* abase = (const char*)feats + (size_t)arow*TOT*2 + g*16;
    const char* bbase = (const char*)hw16 + (size_t)(pt*16+c)*TOT*2 + g*16;
    f32x4 a0=(f32x4){0.f,0.f,0.f,0.f}, a1=a0, a2=a0, a3=a0;
    for (int kc=0;kc<TOT/32;kc+=4){
        bf16x8 af0 =*(const bf16x8*)(abase + (size_t)kc*64);
        bf16x8 bf0 =*(const bf16x8*)(bbase + (size_t)kc*64);
        bf16x8 af1 =*(const bf16x8*)(abase + (size_t)(kc+1)*64);
        bf16x8 bf1 =*(const bf16x8*)(bbase + (size_t)(kc+1)*64);
        bf16x8 af2 =*(const bf16x8*)(abase + (size_t)(kc+2)*64);
        bf16x8 bf2 =*(const bf16x8*)(bbase + (size_t)(kc+2)*64);
        bf16x8 af3 =*(const bf16x8*)(abase + (size_t)(kc+3)*64);
        bf16x8 bf3 =*(const bf16x8*)(bbase + (size_t)(kc+3)*64);
        a0=__builtin_amdgcn_mfma_f32_16x16x32_bf16(af0,bf0,a0,0,0,0);
        a1=__builtin_amdgcn_mfma_f32_16x16x32_bf16(af1,bf1,a1,0,0,0);
        a2=__builtin_amdgcn_mfma_f32_16x16x32_bf16(af2,bf2,a2,0,0,0);
        a3=__builtin_amdgcn_mfma_f32_16x16x32_bf16(af3,bf3,a3,0,0,0);
    }
    f32x4 acc = (a0+a1)+(a2+a3);
    int col = pt*16 + c;
    #pragma unroll
    for (int q=0;q<4;++q){
        int row = m0 + rt*16 + g*4 + q;
        if (row < BB*NN && col < PP)
            out[(size_t)row*PP + col] = acc[q] + hb[col];
    }
}

extern "C" void kernel_launch(void* const* d_in, const int* in_sizes, int n_in,
                              void* d_out, int out_size, void* d_ws, size_t ws_size,
                              hipStream_t stream)
{
    const float* x      = (const float*)d_in[0];
    const float* xfut   = (const float*)d_in[1];
    const float* adj    = (const float*)d_in[2];
    const float* fp_w   = (const float*)d_in[3];
    const float* fp_b   = (const float*)d_in[4];
    const float* inlng  = (const float*)d_in[5];
    const float* inlnb  = (const float*)d_in[6];
    const float* q_w    = (const float*)d_in[7];
    const float* q_b    = (const float*)d_in[8];
    const float* k_w    = (const float*)d_in[9];
    const float* k_b    = (const float*)d_in[10];
    const float* nemb   = (const float*)d_in[11];
    const float* galpha = (const float*)d_in[12];
    const float* wk     = (const float*)d_in[13];
    const float* mk     = (const float*)d_in[14];
    const float* lncg   = (const float*)d_in[15];
    const float* lncb   = (const float*)d_in[16];
    const float* lntg   = (const float*)d_in[17];
    const float* lntb   = (const float*)d_in[18];
    const float* lnfg   = (const float*)d_in[19];
    const float* lnfb   = (const float*)d_in[20];
    const float* lnsg   = (const float*)d_in[21];
    const float* lnsb   = (const float*)d_in[22];
    const float* tw     = (const float*)d_in[23];
    const float* tb     = (const float*)d_in[24];
    const float* fw     = (const float*)d_in[25];
    const float* fb     = (const float*)d_in[26];
    const float* sw     = (const float*)d_in[27];
    const float* sb     = (const float*)d_in[28];
    const float* futw   = (const float*)d_in[29];
    const float* futb   = (const float*)d_in[30];
    const float* hw     = (const float*)d_in[31];
    const float* hb     = (const float*)d_in[32];
    (void)in_sizes; (void)n_in; (void)out_size; (void)ws_size;
    float* out = (float*)d_out;
    float* ws = (float*)d_ws;
    const size_t HSZ = (size_t)BB*NN*SS*HH;

    float* h = ws;
    unsigned char* comb8 = (unsigned char*)(h + HSZ);
    unsigned char* xpg8  = comb8 + (size_t)BB*KC8*(size_t)MP*8;
    unsigned short* wimg  = (unsigned short*)(xpg8 + (size_t)BB*KC8*(size_t)DD*8);
    unsigned short* qpack = wimg + (size_t)NBLK*WIMG_SZ;
    unsigned short* kpack = qpack + (size_t)BB*8*MP*8;
    __hip_bfloat16* feats16 = (__hip_bfloat16*)(kpack + (size_t)BB*8*MP*8);
    __hip_bfloat16* hw16    = feats16 + (size_t)BB*NN*TOT;
    float* adjsum   = (float*)(hw16 + (size_t)32*TOT);
    int*   meta_idx = (int*)(adjsum + NN);
    float* meta_p   = (float*)(meta_idx + (size_t)BB*NN*5);
    float* meta_inv = meta_p + (size_t)BB*NN*5;

    k_prepw<<<NBLK,256,0,stream>>>(wk, mk, tw, fw, sw, wimg);
    k_prep_head<<<(32*TOT)/256,256,0,stream>>>(hw, hw16);
    k_adjsum<<<(NN+3)/4,256,0,stream>>>(adj, adjsum);
    k_fut<<<BB*NN,256,0,stream>>>(xfut, futw, futb, feats16);
    k_front<<<BB*NN,256,0,stream>>>(x, fp_w, fp_b, inlng, inlnb, nemb,
                                    q_w,q_b,k_w,k_b, h, qpack, kpack);
    dim3 gq5(MP/32, BB);
    k_qkt_top5<<<gq5,256,0,stream>>>(qpack, kpack, adjsum, galpha,
                                     meta_idx, meta_p, meta_inv);
    k_blend<<<BB*NN,256,0,stream>>>(adj, galpha, meta_idx, meta_p, comb8);
    // zero the K-pad rows of xpg8 (kc in [179,184))
    for (int b2=0;b2<BB;++b2)
        hipMemsetAsync(xpg8 + ((size_t)b2*KC8+179)*(size_t)DD*8, 0,
                       (size_t)5*DD*8, stream);
    // iter 0
    k_mixer2<<<2874,512,0,stream>>>(h, xpg8, (const unsigned short*)nullptr,
        wimg, lncg,lncb, lntg,lntb, lnfg,lnfb, lnsg,lnsb, tb, fb);
    k_bmm_mfma<<<2688,256,0,stream>>>(comb8, xpg8, sb, h, meta_inv,
        (unsigned short*)feats16, (__hip_bfloat16*)nullptr);
    // iter 1
    k_mixer2<<<2874,512,0,stream>>>(h, xpg8, (const unsigned short*)feats16,
        wimg + WIMG_SZ, lncg+HH,lncb+HH, lntg+HH,lntb+HH, lnfg+HH,lnfb+HH, lnsg+HH,lnsb+HH,
        tb+SS, fb+HH);
    k_bmm_mfma<<<2688,256,0,stream>>>(comb8, xpg8, sb+HH, h, meta_inv,
        (unsigned short*)nullptr, feats16);
    k_head_mfma<<<(BB*NN+31)/32,256,0,stream>>>(feats16, hw16, hb, out);
}

// Round 20
// 431.408 us; speedup vs baseline: 1.0531x; 1.0531x over previous
//
#include <hip/hip_runtime.h>
#include <hip/hip_bf16.h>
#include <math.h>

#define BB 4
#define NN 1437
#define SS 56
#define PP 28
#define FIN 10
#define FFUT 6
#define HH 64
#define NBLK 2
#define TOPK 5
#define DD (SS*HH)     /* 3584 */
#define FD (PP*HH)     /* 1792 */
#define TOT (DD+FD)    /* 5376 */
#define MP 1536        /* padded M (12*128) */
#define KP 1472        /* padded K (46*32)  */
#define KC8 (KP/8)     /* 184 */
#define NT (KP/32)     /* 46 K-steps */
#define WIMG_SZ 16384  /* shorts per mixer-block weight image */

typedef __attribute__((ext_vector_type(8))) __bf16 bf16x8;
typedef __attribute__((ext_vector_type(4))) float  f32x4;
typedef unsigned long long u64;

// h: permuted intra-row layout, element (s,f) at s*64 + (f&15)*4 + (f>>4).
// spat0 (bmm iter0 out): same permuted layout, bf16, row stride TOT, in feats16's h-region.
// comb8: UNNORMALIZED fp8 e4m3, K-PACKED [b][kc(184)][MP][8]; per-row inv in bmm epilogue.
// xpg8: fp8 e4m3 K-packed [b][KC8][DD][8] bytes.

__device__ __forceinline__ float gelu_fast(float x){
    float x2 = x*x;
    float u  = __builtin_fmaf(0.044715f*x2, x, x);
    float e  = __builtin_amdgcn_exp2f(2.3022077f*u);
    float r  = __builtin_amdgcn_rcpf(e+1.f);
    return x - x*r;
}
template<int C>
__device__ __forceinline__ float dppadd(float v){
    int x = __builtin_amdgcn_mov_dpp(__float_as_int(v), C, 0xF, 0xF, true);
    return v + __int_as_float(x);
}
__device__ __forceinline__ float row16_sum(float v){
    v = dppadd<0xB1>(v);
    v = dppadd<0x4E>(v);
    v = dppadd<0x141>(v);
    v = dppadd<0x140>(v);
    return v;
}
__device__ __forceinline__ float wave_sum64(float v){
    v = row16_sum(v);
    v += __shfl_xor(v,16,64);
    v += __shfl_xor(v,32,64);
    return v;
}
__device__ __forceinline__ void async_load16(const void* g, void* l){
    __builtin_amdgcn_global_load_lds(
        (const __attribute__((address_space(1))) void*)g,
        (__attribute__((address_space(3))) void*)l, 16, 0, 0);
}
__device__ __forceinline__ unsigned short f2bf(float x){
    unsigned int u = __float_as_uint(x);
    unsigned int r = (u + 0x7fffu + ((u>>16)&1u)) >> 16;
    return (unsigned short)r;
}
__device__ __forceinline__ unsigned int cvtpk_bf16(float lo, float hi){
    unsigned int r;
    asm("v_cvt_pk_bf16_f32 %0, %1, %2" : "=v"(r) : "v"(lo), "v"(hi));
    return r;
}
__device__ __forceinline__ float bf2f(unsigned short u){
    return __uint_as_float(((unsigned int)u)<<16);
}
__device__ __forceinline__ unsigned char f2fp8(float x){
    return (unsigned char)(__builtin_amdgcn_cvt_pk_fp8_f32(x, 0.f, 0, false) & 0xFF);
}
__device__ __forceinline__ unsigned int pack4fp8(float a, float b, float c, float d){
    int lo = __builtin_amdgcn_cvt_pk_fp8_f32(a, b, 0, false);
    return (unsigned int)__builtin_amdgcn_cvt_pk_fp8_f32(c, d, lo, true);
}
__device__ __forceinline__ u64 umax64(u64 a, u64 b){return a>b?a:b;}
__device__ __forceinline__ u64 umin64(u64 a, u64 b){return a<b?a:b;}

#define INS5(a0,a1,a2,a3,a4,x) do{ u64 t_=(x); \
    u64 n0_=umax64(a0,t_), t1_=umin64(a0,t_); \
    u64 n1_=umax64(a1,t1_), t2_=umin64(a1,t1_); \
    u64 n2_=umax64(a2,t2_), t3_=umin64(a2,t2_); \
    u64 n3_=umax64(a3,t3_), t4_=umin64(a3,t3_); \
    u64 n4_=umax64(a4,t4_); \
    a0=n0_;a1=n1_;a2=n2_;a3=n3_;a4=n4_; }while(0)

#define MERGE5(a0,a1,a2,a3,a4,b0,b1,b2,b3,b4) do{ \
    u64 o0_=umax64(a0,(b0)); \
    u64 o1_=umax64(umax64((b1),umin64(a0,(b0))),a1); \
    u64 o2_=umax64(umax64((b2),umin64(a0,(b1))),umax64(umin64(a1,(b0)),a2)); \
    u64 o3_=umax64(umax64((b3),umin64(a0,(b2))),umax64(umin64(a1,(b1)),umax64(umin64(a2,(b0)),a3))); \
    u64 o4_=umax64(umax64((b4),umin64(a0,(b3))),umax64(umax64(umin64(a1,(b2)),umin64(a2,(b1))),umax64(umin64(a3,(b0)),a4))); \
    a0=o0_;a1=o1_;a2=o2_;a3=o3_;a4=o4_; }while(0)

// ------- front -------
__global__ __launch_bounds__(256) void k_front(
    const float* __restrict__ x, const float* __restrict__ fpw, const float* __restrict__ fpb,
    const float* __restrict__ lng, const float* __restrict__ lnb,
    const float* __restrict__ nemb,
    const float* __restrict__ qw, const float* __restrict__ qb,
    const float* __restrict__ kw, const float* __restrict__ kb,
    float* __restrict__ h,
    unsigned short* __restrict__ qpack, unsigned short* __restrict__ kpack)
{
    int bn = blockIdx.x; int n = bn % NN;
    int tid=threadIdx.x; int lane=tid&63; int wv=tid>>6;
    __shared__ float xin[SS*FIN];
    __shared__ float wlds[HH*FIN];
    __shared__ float rw[SS];
    __shared__ float rsum;
    __shared__ float red[4][HH];
    __shared__ float ctxs[HH];
    for (int i=tid;i<SS*FIN;i+=256) xin[i]=x[(size_t)bn*SS*FIN+i];
    for (int i=tid;i<HH*FIN;i+=256) wlds[i]=fpw[i];
    if (tid<SS) rw[tid]=expf(-(float)(SS-tid)/14.0f);
    __syncthreads();
    if (tid==0){ float s=0.f; for(int i=0;i<SS;++i) s+=rw[i]; rsum=s; }
    __syncthreads();
    float inv_rs = 1.0f/rsum;
    float ev = nemb[(size_t)n*HH+lane];
    float ss = wave_sum64(ev*ev);
    float el = ev / fmaxf(sqrtf(ss), 1e-12f);
    float gg=lng[lane], bv=lnb[lane], fb0=fpb[lane];
    int paddr = (lane&15)*4 + (lane>>4);
    float cacc=0.f;
    for (int s=wv;s<SS;s+=4){
        float v=fb0;
        #pragma unroll
        for (int c=0;c<FIN;++c) v += xin[s*FIN+c]*wlds[lane*FIN+c];
        float m = wave_sum64(v)*(1.f/HH);
        float d = v-m;
        float va = wave_sum64(d*d)*(1.f/HH);
        float hn = d*rsqrtf(va+1e-5f)*gg + bv + el;
        h[((size_t)bn*SS+s)*HH + paddr]=hn;
        cacc += hn * rw[s]*inv_rs;
    }
    red[wv][lane]=cacc;
    __syncthreads();
    if (wv==0) ctxs[lane]=red[0][lane]+red[1][lane]+red[2][lane]+red[3][lane];
    __syncthreads();
    if (wv==0){
        const float4* qr = reinterpret_cast<const float4*>(qw + (size_t)lane*HH);
        const float4* kr = reinterpret_cast<const float4*>(kw + (size_t)lane*HH);
        float q=qb[lane], k=kb[lane];
        #pragma unroll 4
        for (int t=0;t<16;++t){
            float4 qv=qr[t], kv=kr[t];
            float c0=ctxs[4*t], c1=ctxs[4*t+1], c2=ctxs[4*t+2], c3=ctxs[4*t+3];
            q += qv.x*c0+qv.y*c1+qv.z*c2+qv.w*c3;
            k += kv.x*c0+kv.y*c1+kv.z*c2+kv.w*c3;
        }
        int b = bn/NN, m = bn%NN;
        size_t off = (size_t)b*8*MP*8 + (size_t)(lane>>3)*MP*8 + (size_t)m*8 + (lane&7);
        qpack[off]=f2bf(q); kpack[off]=f2bf(k);
    }
}

// ---- adjsum ----
__global__ __launch_bounds__(256) void k_adjsum(
    const float* __restrict__ adj, float* __restrict__ adjsum)
{
    int m = blockIdx.x*4 + (threadIdx.x>>6);
    int lane = threadIdx.x & 63;
    if (m >= NN) return;
    const float* row = adj + (size_t)m*NN;
    float s=0.f;
    for (int n=lane;n<NN;n+=64) s += row[n];
    s = wave_sum64(s);
    if (lane==0) adjsum[m]=s;
}

// ---- fused QK^T + top-5 ----
__global__ __launch_bounds__(256) void k_qkt_top5(
    const unsigned short* __restrict__ qp, const unsigned short* __restrict__ kp,
    const float* __restrict__ adjsum, const float* __restrict__ galpha,
    int* __restrict__ meta_idx, float* __restrict__ meta_p, float* __restrict__ meta_inv)
{
    int m0 = blockIdx.x*32; int b = blockIdx.y;
    int tid=threadIdx.x, lane=tid&63, w=tid>>6;
    int g=lane>>4, c15=lane&15;
    int wr=w>>1, wc=w&1;
    __shared__ u64 mls[64][5];

    const unsigned short* qb2 = qp + (size_t)b*8*MP*8;
    const unsigned short* kb2 = kp + (size_t)b*8*MP*8;
    bf16x8 af0 = *(const bf16x8*)(qb2 + ((size_t)(0*4+g)*MP + m0+wr*16+c15)*8);
    bf16x8 af1 = *(const bf16x8*)(qb2 + ((size_t)(1*4+g)*MP + m0+wr*16+c15)*8);

    u64 A0=0,A1=0,A2=0,A3=0,A4=0;
    u64 B0=0,B1=0,B2=0,B3=0,B4=0;
    u64 C0=0,C1=0,C2=0,C3=0,C4=0;
    u64 D0=0,D1=0,D2=0,D3=0,D4=0;

    for (int t=0;t<12;++t){
        int n0 = t*128;
        f32x4 acc[4];
        #pragma unroll
        for (int j=0;j<4;++j) acc[j]=(f32x4){0.f,0.f,0.f,0.f};
        #pragma unroll
        for (int j=0;j<4;++j){
            bf16x8 b0 = *(const bf16x8*)(kb2 + ((size_t)(0*4+g)*MP + n0+wc*64+j*16+c15)*8);
            bf16x8 b1 = *(const bf16x8*)(kb2 + ((size_t)(1*4+g)*MP + n0+wc*64+j*16+c15)*8);
            acc[j]=__builtin_amdgcn_mfma_f32_16x16x32_bf16(af0,b0,acc[j],0,0,0);
            acc[j]=__builtin_amdgcn_mfma_f32_16x16x32_bf16(af1,b1,acc[j],0,0,0);
        }
        #pragma unroll
        for (int j=0;j<4;++j){
            int n = n0 + wc*64 + j*16 + c15;
            bool ok = (n < NN);
            unsigned int lowk = 0xFFFFFFFFu - (unsigned)n;
            #define MKKEY(Q) ({ \
                float v_ = acc[j][Q]*0.125f; \
                v_ = fminf(fmaxf(v_,0.f),10.f); \
                ok ? (((u64)__float_as_uint(v_)<<32)|(u64)lowk) : 0ULL; })
            { u64 k_=MKKEY(0); INS5(A0,A1,A2,A3,A4,k_); }
            { u64 k_=MKKEY(1); INS5(B0,B1,B2,B3,B4,k_); }
            { u64 k_=MKKEY(2); INS5(C0,C1,C2,C3,C4,k_); }
            { u64 k_=MKKEY(3); INS5(D0,D1,D2,D3,D4,k_); }
            #undef MKKEY
        }
    }
    #pragma unroll
    for (int off=1; off<16; off<<=1){
        u64 t0,t1,t2,t3,t4;
        t0=__shfl_xor(A0,off,64); t1=__shfl_xor(A1,off,64); t2=__shfl_xor(A2,off,64); t3=__shfl_xor(A3,off,64); t4=__shfl_xor(A4,off,64);
        MERGE5(A0,A1,A2,A3,A4,t0,t1,t2,t3,t4);
        t0=__shfl_xor(B0,off,64); t1=__shfl_xor(B1,off,64); t2=__shfl_xor(B2,off,64); t3=__shfl_xor(B3,off,64); t4=__shfl_xor(B4,off,64);
        MERGE5(B0,B1,B2,B3,B4,t0,t1,t2,t3,t4);
        t0=__shfl_xor(C0,off,64); t1=__shfl_xor(C1,off,64); t2=__shfl_xor(C2,off,64); t3=__shfl_xor(C3,off,64); t4=__shfl_xor(C4,off,64);
        MERGE5(C0,C1,C2,C3,C4,t0,t1,t2,t3,t4);
        t0=__shfl_xor(D0,off,64); t1=__shfl_xor(D1,off,64); t2=__shfl_xor(D2,off,64); t3=__shfl_xor(D3,off,64); t4=__shfl_xor(D4,off,64);
        MERGE5(D0,D1,D2,D3,D4,t0,t1,t2,t3,t4);
    }
    if (c15==0){
        int rb = wr*16 + g*4;
        mls[(rb+0)*2+wc][0]=A0; mls[(rb+0)*2+wc][1]=A1; mls[(rb+0)*2+wc][2]=A2; mls[(rb+0)*2+wc][3]=A3; mls[(rb+0)*2+wc][4]=A4;
        mls[(rb+1)*2+wc][0]=B0; mls[(rb+1)*2+wc][1]=B1; mls[(rb+1)*2+wc][2]=B2; mls[(rb+1)*2+wc][3]=B3; mls[(rb+1)*2+wc][4]=B4;
        mls[(rb+2)*2+wc][0]=C0; mls[(rb+2)*2+wc][1]=C1; mls[(rb+2)*2+wc][2]=C2; mls[(rb+2)*2+wc][3]=C3; mls[(rb+2)*2+wc][4]=C4;
        mls[(rb+3)*2+wc][0]=D0; mls[(rb+3)*2+wc][1]=D1; mls[(rb+3)*2+wc][2]=D2; mls[(rb+3)*2+wc][3]=D3; mls[(rb+3)*2+wc][4]=D4;
    }
    __syncthreads();
    if (tid < 32){
        int m = m0 + tid;
        if (m < NN){
            u64 u0=mls[tid*2][0],u1=mls[tid*2][1],u2=mls[tid*2][2],u3=mls[tid*2][3],u4=mls[tid*2][4];
            MERGE5(u0,u1,u2,u3,u4, mls[tid*2+1][0],mls[tid*2+1][1],mls[tid*2+1][2],mls[tid*2+1][3],mls[tid*2+1][4]);
            float s0=__uint_as_float((unsigned)(u0>>32)), s1=__uint_as_float((unsigned)(u1>>32)),
                  s2=__uint_as_float((unsigned)(u2>>32)), s3=__uint_as_float((unsigned)(u3>>32)),
                  s4=__uint_as_float((unsigned)(u4>>32));
            int i0=(int)(0xFFFFFFFFu-(unsigned)u0), i1=(int)(0xFFFFFFFFu-(unsigned)u1),
                i2=(int)(0xFFFFFFFFu-(unsigned)u2), i3=(int)(0xFFFFFFFFu-(unsigned)u3),
                i4=(int)(0xFFFFFFFFu-(unsigned)u4);
            float e0=1.f, e1=expf(s1-s0), e2=expf(s2-s0), e3=expf(s3-s0), e4=expf(s4-s0);
            float den=e0+e1+e2+e3+e4;
            float alpha=1.f/(1.f+expf(-galpha[0]));
            float oma=(1.f-alpha)/den;
            size_t base = ((size_t)b*NN + m)*5;
            meta_idx[base+0]=i0; meta_idx[base+1]=i1; meta_idx[base+2]=i2; meta_idx[base+3]=i3; meta_idx[base+4]=i4;
            meta_p[base+0]=oma*e0; meta_p[base+1]=oma*e1; meta_p[base+2]=oma*e2; meta_p[base+3]=oma*e3; meta_p[base+4]=oma*e4;
            meta_inv[(size_t)b*NN+m] = 1.f/fmaxf(alpha*adjsum[m] + (1.f-alpha), 1e-12f);
        }
    }
}

// ---- blend: comb8 K-packed [b][kc][MP][8] = fp8(alpha*adj + top5 fixups), UNNORMALIZED ----
__global__ __launch_bounds__(256) void k_blend(
    const float* __restrict__ adj, const float* __restrict__ galpha,
    const int* __restrict__ meta_idx, const float* __restrict__ meta_p,
    unsigned char* __restrict__ comb8)
{
    int bid = blockIdx.x;
    int xx = bid & 7, ii = bid >> 3;
    int lin = (xx < 4) ? xx*719 + ii : 2876 + (xx-4)*718 + ii;   // 5748 = 4*719+4*718
    int b = lin / NN, m = lin - b*NN;
    int tid=threadIdx.x;
    size_t base = ((size_t)b*NN + m)*5;
    int i0=meta_idx[base+0], i1=meta_idx[base+1], i2=meta_idx[base+2],
        i3=meta_idx[base+3], i4=meta_idx[base+4];
    float p0=meta_p[base+0], p1=meta_p[base+1], p2=meta_p[base+2],
          p3=meta_p[base+3], p4=meta_p[base+4];
    float alpha=1.f/(1.f+expf(-galpha[0]));
    const float* arow = adj + (size_t)m*NN;
    unsigned char* dst = comb8 + (size_t)b*KC8*(size_t)MP*8;
    for (int n4=tid; n4<KP/4; n4+=256){
        float v[4];
        #pragma unroll
        for (int k=0;k<4;++k){
            int n = n4*4+k;
            float vv = 0.f;
            if (n<NN){
                vv = alpha*arow[n];
                vv += (n==i0)?p0:0.f;
                vv += (n==i1)?p1:0.f;
                vv += (n==i2)?p2:0.f;
                vv += (n==i3)?p3:0.f;
                vv += (n==i4)?p4:0.f;
            }
            v[k]=vv;
        }
        int kc = n4>>1, half = n4&1;
        *reinterpret_cast<unsigned int*>(dst + ((size_t)kc*MP + m)*8 + half*4) =
            pack4fp8(v[0],v[1],v[2],v[3]);
    }
}

// ---- prep: weight images ----
__global__ __launch_bounds__(256) void k_prepw(
    const float* __restrict__ wk, const float* __restrict__ mk,
    const float* __restrict__ tw, const float* __restrict__ fw,
    const float* __restrict__ sw, unsigned short* __restrict__ wimg)
{
    int i = blockIdx.x; int tid = threadIdx.x;
    const float* wki = wk + i*7;
    const float* mki = mk + i*28;
    const float* twi = tw + i*SS*SS;
    const float* fwi = fw + i*HH*HH;
    const float* swi = sw + i*HH*HH;
    unsigned short* o = wimg + (size_t)i*WIMG_SZ;
    for (int e=tid; e<4096; e+=256){
        int r = e>>6, k = e&63;
        int swz = ((k*2) ^ ((r&7)<<4)) >> 1;
        float mv = 0.f;
        if (r<SS && k<SS){
            int a = k-r+3;  if (a>=0 && a<7)  mv += wki[a];
            int b2= k-r+13; if (b2>=0 && b2<28) mv += mki[b2];
        }
        o[r*64 + swz] = f2bf(mv);
        float tv = (r<SS && k<SS) ? twi[r*SS+k] : 0.f;
        o[4096 + r*64 + swz] = f2bf(tv);
        int pk = (k>>3)*512 + r*8 + (k&7);
        o[8192  + pk] = f2bf(fwi[r*HH+k]);
        o[12288 + pk] = f2bf(swi[r*HH+k]);
    }
}

// ---- prep head ----
__global__ __launch_bounds__(256) void k_prep_head(
    const float* __restrict__ hw, __hip_bfloat16* __restrict__ hw16)
{
    int i = blockIdx.x*256 + threadIdx.x;
    int r = i / TOT, k = i - r*TOT;
    float v = (r<PP) ? hw[(size_t)r*TOT + k] : 0.f;
    hw16[i] = __float2bfloat16(v);
}

// ---- fut ----
__global__ __launch_bounds__(256) void k_fut(
    const float* __restrict__ xf, const float* __restrict__ fw,
    const float* __restrict__ fbias, __hip_bfloat16* __restrict__ feats)
{
    int bn=blockIdx.x, tid=threadIdx.x;
    __shared__ float fwl[HH*FFUT];
    __shared__ float fbl[HH];
    __shared__ float xfl[PP*FFUT];
    for (int i=tid;i<HH*FFUT;i+=256) fwl[i]=fw[i];
    if (tid<HH) fbl[tid]=fbias[tid];
    for (int i=tid;i<PP*FFUT;i+=256) xfl[i]=xf[(size_t)bn*PP*FFUT+i];
    __syncthreads();
    __hip_bfloat16* dst = feats + (size_t)bn*TOT + DD;
    for (int q=tid;q<FD;q+=256){
        int pp=q>>6, hh2=q&63;
        float v=fbl[hh2];
        #pragma unroll
        for (int c2=0;c2<FFUT;++c2) v += xfl[pp*FFUT+c2]*fwl[hh2*FFUT+c2];
        dst[q]=__float2bfloat16(v);
    }
}

// ---------------- MFMA mixer block (xs double-buffered; 5 barriers) ----------------
__global__ __launch_bounds__(256) void k_mixer2(
    float* __restrict__ h, unsigned char* __restrict__ xpg8,
    const unsigned short* __restrict__ spat_in,
    const unsigned short* __restrict__ wimg,
    const float* __restrict__ lncg, const float* __restrict__ lncb,
    const float* __restrict__ lntg, const float* __restrict__ lntb,
    const float* __restrict__ lnfg, const float* __restrict__ lnfb,
    const float* __restrict__ lnsg, const float* __restrict__ lnsb,
    const float* __restrict__ tb, const float* __restrict__ fb)
{
    int bid = blockIdx.x;
    int xx = bid & 7, ii = bid >> 3;
    int bn = (xx < 4) ? xx*719 + ii : 2876 + (xx-4)*718 + ii;
    int tid=threadIdx.x, lane=tid&63, w=tid>>6;
    int g=lane>>4, c=lane&15;
    __shared__ unsigned short wbuf[2][4096];
    __shared__ unsigned short xsA[4096];
    __shared__ unsigned short xsB[4096];
    __shared__ float prm[640];

    const char* wsrc=(const char*)wimg;
#define LOADW(SLOTB, BUFP) do{ \
    async_load16(wsrc+(size_t)(SLOTB)+((size_t)tid)*16,       (char*)(BUFP)+(w*64)*16); \
    async_load16(wsrc+(size_t)(SLOTB)+((size_t)(256+tid))*16, (char*)(BUFP)+((256+w*64))*16); } while(0)

    LOADW(0,    wbuf[0]);
    LOADW(8192, wbuf[1]);
    if (tid<64){
        prm[tid]      =lncg[tid]; prm[64+tid] =lncb[tid];
        prm[128+tid]  =lntg[tid]; prm[192+tid]=lntb[tid];
        prm[256+tid]  =lnfg[tid]; prm[320+tid]=lnfb[tid];
        prm[384+tid]  =lnsg[tid]; prm[448+tid]=lnsb[tid];
        prm[512+tid]  =(tid<SS)?tb[tid]:0.f;
        prm[576+tid]  =fb[tid];
    }
    float xl[4][4];
    float* hb = h + (size_t)bn*DD;
    int srow = 16*w + 4*g;
    #pragma unroll
    for (int q=0;q<4;++q){
        int s=srow+q;
        if (s<SS){
            const float4 v4 = *reinterpret_cast<const float4*>(hb + s*HH + c*4);
            float a0=v4.x, a1=v4.y, a2=v4.z, a3=v4.w;
            if (spat_in){
                ushort4 sv = *reinterpret_cast<const ushort4*>(spat_in + (size_t)bn*TOT + s*HH + c*4);
                a0 += bf2f(sv.x); a1 += bf2f(sv.y); a2 += bf2f(sv.z); a3 += bf2f(sv.w);
            }
            xl[q][0]=a0; xl[q][1]=a1; xl[q][2]=a2; xl[q][3]=a3;
        } else {
            xl[q][0]=0.f; xl[q][1]=0.f; xl[q][2]=0.f; xl[q][3]=0.f;
        }
    }
    __syncthreads();   // S0: prm ready

    float xn[4][4];
    f32x4 acc[4];

#define LNSTAGE(GOFF,BOFF) do{ \
    _Pragma("unroll") \
    for (int q=0;q<4;++q){ \
        float sv = xl[q][0]+xl[q][1]+xl[q][2]+xl[q][3]; \
        float s2 = xl[q][0]*xl[q][0]+xl[q][1]*xl[q][1]+xl[q][2]*xl[q][2]+xl[q][3]*xl[q][3]; \
        sv = row16_sum(sv); \
        s2 = row16_sum(s2); \
        float mn = sv*(1.f/64.f); \
        float var = s2*(1.f/64.f)-mn*mn; \
        float rstd = rsqrtf(var+1e-5f); \
        bool ok = (srow+q)<SS; \
        _Pragma("unroll") \
        for (int tj=0;tj<4;++tj){ \
            float v=(xl[q][tj]-mn)*rstd*prm[(GOFF)+tj*16+c]+prm[(BOFF)+tj*16+c]; \
            xn[q][tj]= ok ? v : 0.f; \
        } \
    } }while(0)

#define WRITE_XNP(XS) do{ \
    _Pragma("unroll") \
    for (int qp=0;qp<2;++qp){ \
        int s0=srow+2*qp; \
        _Pragma("unroll") \
        for (int tj=0;tj<4;++tj){ \
            unsigned int pv = cvtpk_bf16(xn[2*qp][tj], xn[2*qp+1][tj]); \
            *(unsigned int*)((char*)(XS) + ((s0>>3)*1024 + (tj*16+c)*16 + (s0&7)*2)) = pv; \
        } \
    } }while(0)

#define WRITE_XNR(XS) do{ \
    _Pragma("unroll") \
    for (int q=0;q<4;++q){ int s=srow+q; \
        _Pragma("unroll") \
        for (int tj=0;tj<4;++tj){ \
            *(unsigned short*)((char*)(XS) + s*128 + (((tj*16+c)*2) ^ ((s&7)<<4))) = f2bf(xn[q][tj]); \
        } \
    } }while(0)

#define MM(APTR,BPTR) do{ \
    _Pragma("unroll") \
    for (int tj=0;tj<4;++tj) acc[tj]=(f32x4){0.f,0.f,0.f,0.f}; \
    _Pragma("unroll") \
    for (int kc=0;kc<2;++kc){ \
        int arow=16*w+c; \
        bf16x8 af=*(const bf16x8*)((const char*)(APTR)+arow*128+((kc*64+g*16)^((arow&7)<<4))); \
        _Pragma("unroll") \
        for (int tj=0;tj<4;++tj){ \
            bf16x8 bf2=*(const bf16x8*)((const char*)(BPTR)+(kc*4+g)*1024+(tj*16+c)*16); \
            acc[tj]=__builtin_amdgcn_mfma_f32_16x16x32_bf16(af,bf2,acc[tj],0,0,0); \
        } \
    } }while(0)

    // ---- conv (banded matmul) ----
    LNSTAGE(0,64); WRITE_XNP(xsA);
    __syncthreads();   // S1: xsA ready; wbuf0/1 loads drained
    MM(&wbuf[0][0], xsA);
    #pragma unroll
    for (int q=0;q<4;++q)
        #pragma unroll
        for (int tj=0;tj<4;++tj) xl[q][tj]+=acc[tj][q];
    // ---- temporal ----
    LNSTAGE(128,192); WRITE_XNP(xsB);
    __syncthreads();   // S2: xsB ready; all waves past conv-MM (wbuf0 free)
    LOADW(16384, wbuf[0]);   // feature weights
    MM(&wbuf[1][0], xsB);
    #pragma unroll
    for (int q=0;q<4;++q){
        float tbv=prm[512+srow+q];
        #pragma unroll
        for (int tj=0;tj<4;++tj) xl[q][tj]+=gelu_fast(acc[tj][q]+tbv);
    }
    // ---- feature ----
    LNSTAGE(256,320); WRITE_XNR(xsA);
    __syncthreads();   // S3: xsA(XNR) ready; feature-load drained; wbuf1 free
    LOADW(24576, wbuf[1]);   // spatial weights
    MM(xsA, &wbuf[0][0]);
    #pragma unroll
    for (int q=0;q<4;++q)
        #pragma unroll
        for (int tj=0;tj<4;++tj) xl[q][tj]+=gelu_fast(acc[tj][q]+prm[576+tj*16+c]);
    // ---- spatial projection ----
    LNSTAGE(384,448); WRITE_XNR(xsB);
    __syncthreads();   // S4: xsB ready; spatial-load drained
    MM(xsB, &wbuf[1][0]);
    int b_=bn/NN, n_=bn%NN;
    unsigned char* xpo = xpg8 + ((size_t)b_*KC8 + (size_t)(n_>>3))*(size_t)DD*8 + (n_&7);
    #pragma unroll
    for (int q=0;q<4;++q){
        int s=srow+q;
        if (s<SS){
            float4 hv; hv.x=xl[q][0]; hv.y=xl[q][1]; hv.z=xl[q][2]; hv.w=xl[q][3];
            *reinterpret_cast<float4*>(hb + s*HH + c*4) = hv;
            #pragma unroll
            for (int tj=0;tj<4;++tj){
                int d = s*HH + tj*16 + c;
                xpo[(size_t)d*8] = f2fp8(acc[tj][q]);
            }
        }
    }
#undef LNSTAGE
#undef WRITE_XNP
#undef WRITE_XNR
#undef MM
#undef LOADW
}

// ---- spatial bmm via fp8 MFMA; all-16B coalesced staging (r16 depth-2 form) ----
__global__ __launch_bounds__(256,8) void k_bmm_mfma(
    const unsigned char* __restrict__ comb8,   // K-packed [b][kc][MP][8]
    const unsigned char* __restrict__ xpg8,    // K-packed [b][kc][DD][8]
    const float* __restrict__ sb,
    const float* __restrict__ h,
    const float* __restrict__ meta_inv,
    unsigned short* __restrict__ spat_out,
    __hip_bfloat16* __restrict__ feats_out)
{
    __shared__ unsigned char As8[3][2048];
    __shared__ unsigned char Bs8[3][4096];
    __shared__ float sinv[64];

    int bid = blockIdx.x;
    int wg = (bid & 7)*336 + (bid >> 3);
    int bm = wg % 24; int tmp2 = wg / 24; int bd = tmp2 % 28; int b = tmp2 / 28;
    int tid=threadIdx.x, lane=tid&63, w=tid>>6;
    int g=lane>>4, c=lane&15;
    int wr=w>>1, wc=w&1;
    int m0=bm*64, d0=bd*128;

    const unsigned char* cbK = comb8 + (size_t)b*KC8*(size_t)MP*8;
    const unsigned char* xb  = xpg8  + (size_t)b*KC8*(size_t)DD*8;

    int l32 = lane & 31;
    const unsigned char* srcA = cbK + ((size_t)w*MP + m0 + l32*2)*8;
    const size_t ASTEP = (size_t)4*MP*8;
    int klB = tid>>6, dpair = tid&63;
    const unsigned char* srcB = xb + ((size_t)klB*DD + d0 + dpair*2)*8;
    const size_t BSTEP = (size_t)4*DD*8;

    if (tid < 64){
        int m = m0 + tid;
        sinv[tid] = (m < NN) ? meta_inv[(size_t)b*NN + m] : 0.f;
    }

    f32x4 acc[2][4];
    #pragma unroll
    for (int i=0;i<2;++i)
        #pragma unroll
        for (int j=0;j<4;++j) acc[i][j]=(f32x4){0.f,0.f,0.f,0.f};

    int aoff[2], boff[4];
    #pragma unroll
    for (int i=0;i<2;++i) aoff[i] = g*512 + (32*wr + 16*i + c)*8;
    #pragma unroll
    for (int j=0;j<4;++j) boff[j] = g*1024 + (64*wc + 16*j + c)*8;

#define STAGE(BUF,T) do { \
    if (lane < 32) async_load16(srcA + (size_t)(T)*ASTEP, (char*)As8[BUF] + w*512 + l32*16); \
    async_load16(srcB + (size_t)(T)*BSTEP, (char*)Bs8[BUF] + tid*16); } while(0)

    STAGE(0,0); STAGE(1,1);
    asm volatile("s_waitcnt vmcnt(2) lgkmcnt(0)" ::: "memory");
    __builtin_amdgcn_s_barrier();

    int cur=0;
    for (int t=0;t<NT;++t){
        if (t+2<NT){
            int nb = cur+2; if (nb>=3) nb-=3;
            STAGE(nb, t+2);
        }
        const char* Ab=(const char*)As8[cur];
        const char* Bb=(const char*)Bs8[cur];
        u64 af[2], bfv[4];
        #pragma unroll
        for (int i=0;i<2;++i) af[i]=*(const u64*)(Ab + aoff[i]);
        #pragma unroll
        for (int j=0;j<4;++j) bfv[j]=*(const u64*)(Bb + boff[j]);
        #pragma unroll
        for (int i=0;i<2;++i)
            #pragma unroll
            for (int j=0;j<4;++j)
                acc[i][j]=__builtin_amdgcn_mfma_f32_16x16x32_fp8_fp8((long)af[i],(long)bfv[j],acc[i][j],0,0,0);
        if (t+2<NT) asm volatile("s_waitcnt vmcnt(2)" ::: "memory");
        else        asm volatile("s_waitcnt vmcnt(0)" ::: "memory");
        __builtin_amdgcn_s_barrier();
        ++cur; if (cur>=3) cur=0;
    }
#undef STAGE

    int row_b = m0 + 32*wr + g*4;
    int s2 = 2*bd + wc;
    float sb0=sb[c], sb1=sb[16+c], sb2=sb[32+c], sb3=sb[48+c];
    #pragma unroll
    for (int i=0;i<2;++i){
        #pragma unroll
        for (int q=0;q<4;++q){
            int m = row_b + 16*i + q;
            if (m < NN){
                float inv = sinv[32*wr + g*4 + 16*i + q];
                if (spat_out){
                    ushort4 pv;
                    pv.x = f2bf(inv*acc[i][0][q] + sb0);
                    pv.y = f2bf(inv*acc[i][1][q] + sb1);
                    pv.z = f2bf(inv*acc[i][2][q] + sb2);
                    pv.w = f2bf(inv*acc[i][3][q] + sb3);
                    *reinterpret_cast<ushort4*>(spat_out + ((size_t)b*NN+m)*TOT + s2*HH + c*4) = pv;
                } else {
                    const float* hp = h + ((size_t)b*NN+m)*DD + s2*HH + c*4;
                    float4 hv = *reinterpret_cast<const float4*>(hp);
                    float nv0 = hv.x + inv*acc[i][0][q] + sb0;
                    float nv1 = hv.y + inv*acc[i][1][q] + sb1;
                    float nv2 = hv.z + inv*acc[i][2][q] + sb2;
                    float nv3 = hv.w + inv*acc[i][3][q] + sb3;
                    size_t fr = ((size_t)b*NN+m)*TOT + (size_t)bd*128 + wc*64;
                    feats_out[fr + c]      = __float2bfloat16(nv0);
                    feats_out[fr + 16 + c] = __float2bfloat16(nv1);
                    feats_out[fr + 32 + c] = __float2bfloat16(nv2);
                    feats_out[fr + 48 + c] = __float2bfloat16(nv3);
                }
            }
        }
    }
}

// ---------------- head GEMM, K-split x4 -> partials ----------------
__global__ __launch_bounds__(256) void k_head_mfma(
    const __hip_bfloat16* __restrict__ feats, const __hip_bfloat16* __restrict__ hw16,
    float* __restrict__ hpart)
{
    int tid=threadIdx.x, lane=tid&63, w=tid>>6;
    int g=lane>>4, c=lane&15;
    int m0=blockIdx.x*32;
    int kq=blockIdx.y;
    int rt=w>>1, pt=w&1;
    int arow = m0 + rt*16 + c;
    if (arow > BB*NN-1) arow = BB*NN-1;
    const char* abase = (const char*)feats + (size_t)arow*TOT*2 + g*16;
    const char* bbase = (const char*)hw16 + (size_t)(pt*16+c)*TOT*2 + g*16;
    f32x4 a0=(f32x4){0.f,0.f,0.f,0.f}, a1=a0;
    int kbeg = kq*42, kend = kbeg+42;   // TOT/32 = 168 = 4*42
    for (int kc=kbeg;kc<kend;kc+=2){
        bf16x8 af0 =*(const bf16x8*)(abase + (size_t)kc*64);
        bf16x8 bf0 =*(const bf16x8*)(bbase + (size_t)kc*64);
        bf16x8 af1 =*(const bf16x8*)(abase + (size_t)(kc+1)*64);
        bf16x8 bf1 =*(const bf16x8*)(bbase + (size_t)(kc+1)*64);
        a0=__builtin_amdgcn_mfma_f32_16x16x32_bf16(af0,bf0,a0,0,0,0);
        a1=__builtin_amdgcn_mfma_f32_16x16x32_bf16(af1,bf1,a1,0,0,0);
    }
    f32x4 acc = a0+a1;
    int col = pt*16 + c;
    #pragma unroll
    for (int q=0;q<4;++q){
        int row = m0 + rt*16 + g*4 + q;
        if (row < BB*NN && col < PP)
            hpart[((size_t)kq*BB*NN + row)*PP + col] = acc[q];
    }
}

__global__ __launch_bounds__(256) void k_head_red(
    const float* __restrict__ hpart, const float* __restrict__ hb,
    float* __restrict__ out)
{
    int idx = blockIdx.x*256 + threadIdx.x;
    const int NTOT = BB*NN*PP;
    if (idx < NTOT){
        float v = hpart[idx] + hpart[(size_t)NTOT + idx]
                + hpart[(size_t)2*NTOT + idx] + hpart[(size_t)3*NTOT + idx];
        out[idx] = v + hb[idx % PP];
    }
}

extern "C" void kernel_launch(void* const* d_in, const int* in_sizes, int n_in,
                              void* d_out, int out_size, void* d_ws, size_t ws_size,
                              hipStream_t stream)
{
    const float* x      = (const float*)d_in[0];
    const float* xfut   = (const float*)d_in[1];
    const float* adj    = (const float*)d_in[2];
    const float* fp_w   = (const float*)d_in[3];
    const float* fp_b   = (const float*)d_in[4];
    const float* inlng  = (const float*)d_in[5];
    const float* inlnb  = (const float*)d_in[6];
    const float* q_w    = (const float*)d_in[7];
    const float* q_b    = (const float*)d_in[8];
    const float* k_w    = (const float*)d_in[9];
    const float* k_b    = (const float*)d_in[10];
    const float* nemb   = (const float*)d_in[11];
    const float* galpha = (const float*)d_in[12];
    const float* wk     = (const float*)d_in[13];
    const float* mk     = (const float*)d_in[14];
    const float* lncg   = (const float*)d_in[15];
    const float* lncb   = (const float*)d_in[16];
    const float* lntg   = (const float*)d_in[17];
    const float* lntb   = (const float*)d_in[18];
    const float* lnfg   = (const float*)d_in[19];
    const float* lnfb   = (const float*)d_in[20];
    const float* lnsg   = (const float*)d_in[21];
    const float* lnsb   = (const float*)d_in[22];
    const float* tw     = (const float*)d_in[23];
    const float* tb     = (const float*)d_in[24];
    const float* fw     = (const float*)d_in[25];
    const float* fb     = (const float*)d_in[26];
    const float* sw     = (const float*)d_in[27];
    const float* sb     = (const float*)d_in[28];
    const float* futw   = (const float*)d_in[29];
    const float* futb   = (const float*)d_in[30];
    const float* hw     = (const float*)d_in[31];
    const float* hb     = (const float*)d_in[32];
    (void)in_sizes; (void)n_in; (void)out_size; (void)ws_size;
    float* out = (float*)d_out;
    float* ws = (float*)d_ws;
    const size_t HSZ = (size_t)BB*NN*SS*HH;

    float* h = ws;
    unsigned char* comb8 = (unsigned char*)(h + HSZ);
    unsigned char* xpg8  = comb8 + (size_t)BB*KC8*(size_t)MP*8;
    unsigned short* wimg  = (unsigned short*)(xpg8 + (size_t)BB*KC8*(size_t)DD*8);
    unsigned short* qpack = wimg + (size_t)NBLK*WIMG_SZ;
    unsigned short* kpack = qpack + (size_t)BB*8*MP*8;
    __hip_bfloat16* feats16 = (__hip_bfloat16*)(kpack + (size_t)BB*8*MP*8);
    __hip_bfloat16* hw16    = feats16 + (size_t)BB*NN*TOT;
    float* adjsum   = (float*)(hw16 + (size_t)32*TOT);
    int*   meta_idx = (int*)(adjsum + NN);
    float* meta_p   = (float*)(meta_idx + (size_t)BB*NN*5);
    float* meta_inv = meta_p + (size_t)BB*NN*5;
    float* hpart    = meta_inv + (size_t)BB*NN;

    k_prepw<<<NBLK,256,0,stream>>>(wk, mk, tw, fw, sw, wimg);
    k_prep_head<<<(32*TOT)/256,256,0,stream>>>(hw, hw16);
    k_adjsum<<<(NN+3)/4,256,0,stream>>>(adj, adjsum);
    k_fut<<<BB*NN,256,0,stream>>>(xfut, futw, futb, feats16);
    k_front<<<BB*NN,256,0,stream>>>(x, fp_w, fp_b, inlng, inlnb, nemb,
                                    q_w,q_b,k_w,k_b, h, qpack, kpack);
    dim3 gq5(MP/32, BB);
    k_qkt_top5<<<gq5,256,0,stream>>>(qpack, kpack, adjsum, galpha,
                                     meta_idx, meta_p, meta_inv);
    k_blend<<<BB*NN,256,0,stream>>>(adj, galpha, meta_idx, meta_p, comb8);
    // zero the K-pad rows of xpg8 (kc in [179,184))
    for (int b2=0;b2<BB;++b2)
        hipMemsetAsync(xpg8 + ((size_t)b2*KC8+179)*(size_t)DD*8, 0,
                       (size_t)5*DD*8, stream);
    // iter 0
    k_mixer2<<<BB*NN,256,0,stream>>>(h, xpg8, (const unsigned short*)nullptr,
        wimg, lncg,lncb, lntg,lntb, lnfg,lnfb, lnsg,lnsb, tb, fb);
    k_bmm_mfma<<<2688,256,0,stream>>>(comb8, xpg8, sb, h, meta_inv,
        (unsigned short*)feats16, (__hip_bfloat16*)nullptr);
    // iter 1
    k_mixer2<<<BB*NN,256,0,stream>>>(h, xpg8, (const unsigned short*)feats16,
        wimg + WIMG_SZ, lncg+HH,lncb+HH, lntg+HH,lntb+HH, lnfg+HH,lnfb+HH, lnsg+HH,lnsb+HH,
        tb+SS, fb+HH);
    k_bmm_mfma<<<2688,256,0,stream>>>(comb8, xpg8, sb+HH, h, meta_inv,
        (unsigned short*)nullptr, feats16);
    dim3 ghead((BB*NN+31)/32, 4);
    k_head_mfma<<<ghead,256,0,stream>>>(feats16, hw16, hpart);
    k_head_red<<<(BB*NN*PP+255)/256,256,0,stream>>>(hpart, hb, out);
}